// Round 12
// baseline (40.179 us; speedup 1.0000x reference)
//
#include <hip/hip_runtime.h>

#define TT 200
#define DD 64
#define BLOCK 256
#define KSH 68      // bf16 halfs per kh row: word-stride 34 = 2 mod 32 -> 2-way-free frag reads
#define CWS 132     // bf16 halfs per cwt row: word-stride 66 = 2 mod 32 -> 2-way-free

typedef unsigned short u16;
typedef unsigned int u32;
typedef __attribute__((ext_vector_type(8))) short short8v;  // MFMA bf16x8 frag
typedef __attribute__((ext_vector_type(4))) float f32x4;    // MFMA acc

union Frag { uint2 h[2]; short8v v; };

__device__ __forceinline__ float bflo(u32 w) {
    union { u32 u; float f; } v; v.u = w << 16; return v.f;
}
__device__ __forceinline__ float bfhi(u32 w) {
    union { u32 u; float f; } v; v.u = w & 0xFFFF0000u; return v.f;
}
__device__ __forceinline__ u16 f2bf(float f) {
    union { float f; u32 u; } v; v.f = f;
    return (u16)((v.u + 0x7FFFu + ((v.u >> 16) & 1u)) >> 16);
}
__device__ __forceinline__ u32 cvt_pk_bf16(float lo, float hi) {
    u32 r;
    asm("v_cvt_pk_bf16_f32 %0, %1, %2" : "=v"(r) : "v"(lo), "v"(hi));
    return r;
}
__device__ __forceinline__ float sigmoid_fast(float x) {
    return __builtin_amdgcn_rcpf(1.0f + __expf(-x));
}

// LDS-only barrier: drain LDS ops, sync, fence scheduler. NO vmcnt drain:
// in-flight chunk loads cross it (R8/R9/R11-validated).
#define BARRIER() do {                                              \
    asm volatile("s_waitcnt lgkmcnt(0)" ::: "memory");              \
    __builtin_amdgcn_sched_barrier(0);                              \
    __builtin_amdgcn_s_barrier();                                   \
    __builtin_amdgcn_sched_barrier(0);                              \
} while (0)

__global__ __launch_bounds__(BLOCK, 4) void attn_pool_kernel(
    const float* __restrict__ queries, const float* __restrict__ keys,
    const int* __restrict__ masks, const float* __restrict__ W1,
    const float* __restrict__ b1, const float* __restrict__ W2,
    const float* __restrict__ b2, const float* __restrict__ W3,
    const float* __restrict__ b3, float* __restrict__ out)
{
    __shared__ __align__(16) u16   lds_kh[TT][KSH];    // 27,200 B
    __shared__ __align__(16) u16   lds_cwt[16][CWS];   // 4,224 B  cols 0..63 CW (q-dep), 64..127 AC
    __shared__ __align__(16) u16   lds_q16[DD];        // 128 B
    __shared__ __align__(16) float lds_s[TT][8];       // 6,400 B  scores fp32
    __shared__ __align__(16) float lds_w[52];          // 208 B
    __shared__ __align__(16) float lds_e[TT];          // 800 B
    __shared__ __align__(16) float red[4];             // 16 B   => ~38.9 KB -> 4 blocks/CU
    float* part = (float*)&lds_s[0][0];                // [4][64] f32 alias (s dead after tail)

    const int b = blockIdx.x;
    const int tid = threadIdx.x;
    const int wave = tid >> 6;
    const int lane = tid & 63;

    // ======== P: issue K chunks 0,1 FIRST (oldest in vmcnt FIFO) ========
    const float4* kp = (const float4*)(keys + (size_t)b * TT * DD);
    float4 L0[4], L1[4], L2[4], L2x;
#pragma unroll
    for (int j = 0; j < 4; ++j) L0[j] = kp[(j << 8) + tid];          // rows 0..63
#pragma unroll
    for (int j = 0; j < 4; ++j) L1[j] = kp[1024 + (j << 8) + tid];   // rows 64..127
    __builtin_amdgcn_sched_barrier(0);

    // ---- batch-scalar loads (younger than L0/L1) ----
    int msk = 0;
    if (tid < TT) msk = masks[(size_t)b * TT + tid];
    const int d_f = tid & 63;
    const int jr = tid >> 6;
    const float w1c0 = W1[(128 + d_f) * 8 + jr];
    const float wbc0 = W1[(64 + d_f) * 8 + jr] - w1c0;
    const float wd0  = W1[(192 + d_f) * 8 + jr];
    const float wac0 = W1[d_f * 8 + jr] + w1c0;
    const float w1c1 = W1[(128 + d_f) * 8 + jr + 4];
    const float wbc1 = W1[(64 + d_f) * 8 + jr + 4] - w1c1;
    const float wd1  = W1[(192 + d_f) * 8 + jr + 4];
    const float wac1 = W1[d_f * 8 + jr + 4] + w1c1;
    const float qd   = queries[(size_t)b * DD + d_f];
    float wv = 0.0f;
    if (tid < 32)       wv = W2[tid];
    else if (tid < 36)  wv = W3[tid - 32];
    else if (tid < 40)  wv = b2[tid - 36];
    else if (tid < 48)  wv = b1[tid - 40];
    else if (tid == 48) wv = b3[0];
    __builtin_amdgcn_sched_barrier(0);

    // ---- stage c0 (waits L0 only; younger loads stay in flight) ----
#pragma unroll
    for (int j = 0; j < 4; ++j) {
        int idx = (j << 8) + tid;
        float4 v = L0[j];
        uint2 wp; wp.x = cvt_pk_bf16(v.x, v.y); wp.y = cvt_pk_bf16(v.z, v.w);
        *(uint2*)&lds_kh[idx >> 4][(idx & 15) << 2] = wp;
    }
    // ---- issue chunk 2 (rows 128..199, incl. 8-row tail) ----
#pragma unroll
    for (int j = 0; j < 4; ++j) L2[j] = kp[2048 + (j << 8) + tid];   // rows 128..191
    L2x = kp[3072 + (tid & 127)];                                    // rows 192..199 (dup for tid>=128)
    __builtin_amdgcn_sched_barrier(0);

    // ---- folds (wait W1/q; L2/L2x younger -> remain in flight) ----
    lds_cwt[jr][64 + d_f]     = f2bf(wac0);
    lds_cwt[jr + 4][64 + d_f] = f2bf(wac1);
    lds_cwt[jr][d_f]          = f2bf(fmaf(qd, wd0, wbc0));
    lds_cwt[jr + 4][d_f]      = f2bf(fmaf(qd, wd1, wbc1));
    if (tid < DD) lds_q16[tid] = f2bf(qd);
    if (tid < 49) lds_w[tid] = wv;
    BARRIER();   // B1: c0 rows + cwt + q16 + w ready

    // ======== pipelined GEMM: compute chunk k || stage chunk k+1 ========
    const int r = lane & 15, g = lane >> 4;
    Frag bf0, bf1, bq0, bq1, aq0, aq1;
    bf0.h[0] = *(const uint2*)&lds_cwt[r][g * 8];
    bf0.h[1] = *(const uint2*)&lds_cwt[r][g * 8 + 4];
    bf1.h[0] = *(const uint2*)&lds_cwt[r][32 + g * 8];
    bf1.h[1] = *(const uint2*)&lds_cwt[r][32 + g * 8 + 4];
    bq0.h[0] = *(const uint2*)&lds_cwt[r][64 + g * 8];
    bq0.h[1] = *(const uint2*)&lds_cwt[r][64 + g * 8 + 4];
    bq1.h[0] = *(const uint2*)&lds_cwt[r][96 + g * 8];
    bq1.h[1] = *(const uint2*)&lds_cwt[r][96 + g * 8 + 4];
    aq0.h[0] = *(const uint2*)&lds_q16[g * 8];
    aq0.h[1] = *(const uint2*)&lds_q16[g * 8 + 4];
    aq1.h[0] = *(const uint2*)&lds_q16[32 + g * 8];
    aq1.h[1] = *(const uint2*)&lds_q16[32 + g * 8 + 4];
    f32x4 zero = {0.0f, 0.0f, 0.0f, 0.0f};
    f32x4 acc_base = __builtin_amdgcn_mfma_f32_16x16x32_bf16(aq1.v, bq1.v, zero, 0, 0, 0);
    acc_base = __builtin_amdgcn_mfma_f32_16x16x32_bf16(aq0.v, bq0.v, acc_base, 0, 0, 0);

    auto gemm_tile = [&](int t0) {
        Frag a0, a1;
        a0.h[0] = *(const uint2*)&lds_kh[t0 + r][g * 8];
        a0.h[1] = *(const uint2*)&lds_kh[t0 + r][g * 8 + 4];
        a1.h[0] = *(const uint2*)&lds_kh[t0 + r][32 + g * 8];
        a1.h[1] = *(const uint2*)&lds_kh[t0 + r][32 + g * 8 + 4];
        f32x4 acc = __builtin_amdgcn_mfma_f32_16x16x32_bf16(a0.v, bf0.v, acc_base, 0, 0, 0);
        acc = __builtin_amdgcn_mfma_f32_16x16x32_bf16(a1.v, bf1.v, acc, 0, 0, 0);
        if (r < 8) {                 // D: col(j)=lane&15, row(t)=g*4+reg
            const int rr = t0 + (g << 2);
            lds_s[rr + 0][r] = acc[0];
            lds_s[rr + 1][r] = acc[1];
            lds_s[rr + 2][r] = acc[2];
            lds_s[rr + 3][r] = acc[3];
        }
    };

    // R0: tiles 0-3 (rows 0-63) || stage c1 (rows 64-127)
    gemm_tile(wave << 4);
#pragma unroll
    for (int j = 0; j < 4; ++j) {
        int idx = 1024 + (j << 8) + tid;
        float4 v = L1[j];
        uint2 wp; wp.x = cvt_pk_bf16(v.x, v.y); wp.y = cvt_pk_bf16(v.z, v.w);
        *(uint2*)&lds_kh[idx >> 4][(idx & 15) << 2] = wp;
    }
    BARRIER();
    // R1: tiles 4-7 || stage c2 (rows 128-199)
    gemm_tile((4 + wave) << 4);
#pragma unroll
    for (int j = 0; j < 4; ++j) {
        int idx = 2048 + (j << 8) + tid;
        float4 v = L2[j];
        uint2 wp; wp.x = cvt_pk_bf16(v.x, v.y); wp.y = cvt_pk_bf16(v.z, v.w);
        *(uint2*)&lds_kh[idx >> 4][(idx & 15) << 2] = wp;
    }
    if (tid < 128) {
        int idx = 3072 + tid;
        float4 v = L2x;
        uint2 wp; wp.x = cvt_pk_bf16(v.x, v.y); wp.y = cvt_pk_bf16(v.z, v.w);
        *(uint2*)&lds_kh[idx >> 4][(idx & 15) << 2] = wp;
    }
    BARRIER();
    // R2: tiles 8-11, plus wave 0 computes the clamped last tile (t0=184;
    // rows 184-191 dup-computed with identical values)
    gemm_tile((8 + wave) << 4);
    if (wave == 0) gemm_tile(TT - 16);
    BARRIER();   // S complete

    // ---- MLP tail + fused esum: 200 threads, 1 row each ----
    float epart = 0.0f;
    if (tid < TT) {
        float4 s0 = *(const float4*)&lds_s[tid][0];
        float4 s1 = *(const float4*)&lds_s[tid][4];
        float4 b1A = *(const float4*)&lds_w[40];
        float4 b1B = *(const float4*)&lds_w[44];
        float h1[8];
        h1[0] = sigmoid_fast(s0.x + b1A.x);
        h1[1] = sigmoid_fast(s0.y + b1A.y);
        h1[2] = sigmoid_fast(s0.z + b1A.z);
        h1[3] = sigmoid_fast(s0.w + b1A.w);
        h1[4] = sigmoid_fast(s1.x + b1B.x);
        h1[5] = sigmoid_fast(s1.y + b1B.y);
        h1[6] = sigmoid_fast(s1.z + b1B.z);
        h1[7] = sigmoid_fast(s1.w + b1B.w);
        float sc = lds_w[48];
#pragma unroll
        for (int c = 0; c < 4; ++c) {
            float h = lds_w[36 + c];
#pragma unroll
            for (int j = 0; j < 8; ++j)
                h = fmaf(h1[j], lds_w[j * 4 + c], h);
            sc = fmaf(sigmoid_fast(h), lds_w[32 + c], sc);
        }
        float e = msk ? __expf(sc) : 0.0f;   // no-max softmax: |score| bounded
        lds_e[tid] = e;
        epart = e;
    }
#pragma unroll
    for (int off = 32; off; off >>= 1) epart += __shfl_xor(epart, off, 64);
    if (lane == 0) red[wave] = epart;
    BARRIER();   // B3: e + red ready; lds_s dead -> part alias live

    // ---- PV from bf16 kh (2-way-free): lane = (half, d-pair) ----
    {
        const int half = lane >> 5;
        const int dp = lane & 31;
        const int d0 = dp << 1;
        const int tbase = (wave << 1) + half;   // 0..7
        float acc0 = 0.0f, acc1 = 0.0f;
#pragma unroll
        for (int i = 0; i < 25; ++i) {
            const int t = tbase + (i << 3);
            u32 kw = *(const u32*)&lds_kh[t][d0];
            float e = lds_e[t];
            acc0 = fmaf(e, bflo(kw), acc0);
            acc1 = fmaf(e, bfhi(kw), acc1);
        }
        acc0 += __shfl_xor(acc0, 32, 64);
        acc1 += __shfl_xor(acc1, 32, 64);
        if (half == 0) {
            float2 wpack; wpack.x = acc0; wpack.y = acc1;
            *(float2*)&part[wave * DD + d0] = wpack;
        }
    }
    BARRIER();   // B4: partials ready

    // ---- epilogue (wave 0): combine + store ----
    if (wave == 0) {
        float tot = red[0] + red[1] + red[2] + red[3];
        float rr = part[lane] + part[DD + lane] + part[2 * DD + lane] + part[3 * DD + lane];
        out[(size_t)b * DD + lane] = rr / tot;
    }
}

extern "C" void kernel_launch(void* const* d_in, const int* in_sizes, int n_in,
                              void* d_out, int out_size, void* d_ws, size_t ws_size,
                              hipStream_t stream) {
    const float* queries = (const float*)d_in[0];
    const float* keys    = (const float*)d_in[1];
    const int*   masks   = (const int*)d_in[2];
    const float* W1      = (const float*)d_in[3];
    const float* b1      = (const float*)d_in[4];
    const float* W2      = (const float*)d_in[5];
    const float* b2      = (const float*)d_in[6];
    const float* W3      = (const float*)d_in[7];
    const float* b3      = (const float*)d_in[8];
    float* out = (float*)d_out;

    const int B = in_sizes[0] / DD;  // 4096
    attn_pool_kernel<<<B, BLOCK, 0, stream>>>(queries, keys, masks, W1, b1, W2, b2, W3, b3, out);
}

// Round 13
// 40.013 us; speedup vs baseline: 1.0042x; 1.0042x over previous
//
#include <hip/hip_runtime.h>

#define TT 200
#define DD 64
#define BLOCK 256
#define KSH 68      // bf16 halfs per kh row: word-stride 34 = 2 mod 32 -> 2-way-free frag reads
#define CWS 132     // bf16 halfs per cwt row: word-stride 66 = 2 mod 32 -> 2-way-free

typedef unsigned short u16;
typedef unsigned int u32;
typedef __attribute__((ext_vector_type(8))) short short8v;  // MFMA bf16x8 frag
typedef __attribute__((ext_vector_type(4))) float f32x4;    // MFMA acc

union Frag { uint2 h[2]; short8v v; };

__device__ __forceinline__ float bflo(u32 w) {
    union { u32 u; float f; } v; v.u = w << 16; return v.f;
}
__device__ __forceinline__ float bfhi(u32 w) {
    union { u32 u; float f; } v; v.u = w & 0xFFFF0000u; return v.f;
}
__device__ __forceinline__ u16 f2bf(float f) {
    union { float f; u32 u; } v; v.f = f;
    return (u16)((v.u + 0x7FFFu + ((v.u >> 16) & 1u)) >> 16);
}
__device__ __forceinline__ u32 cvt_pk_bf16(float lo, float hi) {
    u32 r;
    asm("v_cvt_pk_bf16_f32 %0, %1, %2" : "=v"(r) : "v"(lo), "v"(hi));
    return r;
}
__device__ __forceinline__ float sigmoid_fast(float x) {
    return __builtin_amdgcn_rcpf(1.0f + __expf(-x));
}
__device__ __forceinline__ float readlane_f(float v, int lane) {
    union { float f; int i; } a, b;
    a.f = v;
    b.i = __builtin_amdgcn_readlane(a.i, lane);
    return b.f;
}

// LDS-only barrier: drain LDS ops, sync, fence scheduler. NO vmcnt drain:
// in-flight chunk loads cross it (R8/R9/R11-validated).
#define BARRIER() do {                                              \
    asm volatile("s_waitcnt lgkmcnt(0)" ::: "memory");              \
    __builtin_amdgcn_sched_barrier(0);                              \
    __builtin_amdgcn_s_barrier();                                   \
    __builtin_amdgcn_sched_barrier(0);                              \
} while (0)

__global__ __launch_bounds__(BLOCK, 4) void attn_pool_kernel(
    const float* __restrict__ queries, const float* __restrict__ keys,
    const int* __restrict__ masks, const float* __restrict__ W1,
    const float* __restrict__ b1, const float* __restrict__ W2,
    const float* __restrict__ b2, const float* __restrict__ W3,
    const float* __restrict__ b3, float* __restrict__ out)
{
    __shared__ __align__(16) u16   lds_kh[TT][KSH];    // 27,200 B
    __shared__ __align__(16) u16   lds_cwt[16][CWS];   // 4,224 B  cols 0..63 CW (q-dep), 64..127 AC
    __shared__ __align__(16) u16   lds_q16[DD];        // 128 B
    __shared__ __align__(16) float lds_s[TT][8];       // 6,400 B  scores fp32
    __shared__ __align__(16) float lds_e[TT + 32];     // 928 B (padded: readlane preload over-reads)
    __shared__ __align__(16) float red[4];             // 16 B   => ~38.9 KB -> 4 blocks/CU
    float* part = (float*)&lds_s[0][0];                // [4][64] f32 alias (s dead after tail)

    const int b = blockIdx.x;
    const int tid = threadIdx.x;
    const int wave = tid >> 6;
    const int lane = tid & 63;

    // ======== P: issue K chunks 0,1 FIRST (oldest in vmcnt FIFO) ========
    const float4* kp = (const float4*)(keys + (size_t)b * TT * DD);
    float4 L0[4], L1[4], L2[4], L3;
#pragma unroll
    for (int j = 0; j < 4; ++j) L0[j] = kp[(j << 8) + tid];          // rows 0..63
#pragma unroll
    for (int j = 0; j < 4; ++j) L1[j] = kp[1024 + (j << 8) + tid];   // rows 64..127
    __builtin_amdgcn_sched_barrier(0);

    // ---- batch-scalar loads (younger than L0/L1) ----
    int msk = 0;
    if (tid < TT) msk = masks[(size_t)b * TT + tid];
    const int d_f = tid & 63;
    const int jr = tid >> 6;
    const float w1c0 = W1[(128 + d_f) * 8 + jr];
    const float wbc0 = W1[(64 + d_f) * 8 + jr] - w1c0;
    const float wd0  = W1[(192 + d_f) * 8 + jr];
    const float wac0 = W1[d_f * 8 + jr] + w1c0;
    const float w1c1 = W1[(128 + d_f) * 8 + jr + 4];
    const float wbc1 = W1[(64 + d_f) * 8 + jr + 4] - w1c1;
    const float wd1  = W1[(192 + d_f) * 8 + jr + 4];
    const float wac1 = W1[d_f * 8 + jr + 4] + w1c1;
    const float qd   = queries[(size_t)b * DD + d_f];
    __builtin_amdgcn_sched_barrier(0);

    // ---- stage c0 (waits L0 only; younger loads stay in flight) ----
#pragma unroll
    for (int j = 0; j < 4; ++j) {
        int idx = (j << 8) + tid;
        float4 v = L0[j];
        uint2 wp; wp.x = cvt_pk_bf16(v.x, v.y); wp.y = cvt_pk_bf16(v.z, v.w);
        *(uint2*)&lds_kh[idx >> 4][(idx & 15) << 2] = wp;
    }
    // ---- issue chunks 2,3 ----
#pragma unroll
    for (int j = 0; j < 4; ++j) L2[j] = kp[2048 + (j << 8) + tid];   // rows 128..191
    L3 = kp[3072 + (tid & 127)];                                     // rows 192..199 (dup for tid>=128)
    __builtin_amdgcn_sched_barrier(0);

    // ---- folds (wait W1/q; L2/L3 younger -> remain in flight) ----
    lds_cwt[jr][64 + d_f]     = f2bf(wac0);
    lds_cwt[jr + 4][64 + d_f] = f2bf(wac1);
    lds_cwt[jr][d_f]          = f2bf(fmaf(qd, wd0, wbc0));
    lds_cwt[jr + 4][d_f]      = f2bf(fmaf(qd, wd1, wbc1));
    if (tid < DD) lds_q16[tid] = f2bf(qd);
    BARRIER();   // B1: c0 rows + cwt + q16 ready

    // ======== pipelined GEMM: compute chunk k || stage chunk k+1 ========
    const int r = lane & 15, g = lane >> 4;
    Frag bf0, bf1, bq0, bq1, aq0, aq1;
    bf0.h[0] = *(const uint2*)&lds_cwt[r][g * 8];
    bf0.h[1] = *(const uint2*)&lds_cwt[r][g * 8 + 4];
    bf1.h[0] = *(const uint2*)&lds_cwt[r][32 + g * 8];
    bf1.h[1] = *(const uint2*)&lds_cwt[r][32 + g * 8 + 4];
    bq0.h[0] = *(const uint2*)&lds_cwt[r][64 + g * 8];
    bq0.h[1] = *(const uint2*)&lds_cwt[r][64 + g * 8 + 4];
    bq1.h[0] = *(const uint2*)&lds_cwt[r][96 + g * 8];
    bq1.h[1] = *(const uint2*)&lds_cwt[r][96 + g * 8 + 4];
    aq0.h[0] = *(const uint2*)&lds_q16[g * 8];
    aq0.h[1] = *(const uint2*)&lds_q16[g * 8 + 4];
    aq1.h[0] = *(const uint2*)&lds_q16[32 + g * 8];
    aq1.h[1] = *(const uint2*)&lds_q16[32 + g * 8 + 4];
    f32x4 zero = {0.0f, 0.0f, 0.0f, 0.0f};
    f32x4 acc_base = __builtin_amdgcn_mfma_f32_16x16x32_bf16(aq1.v, bq1.v, zero, 0, 0, 0);
    acc_base = __builtin_amdgcn_mfma_f32_16x16x32_bf16(aq0.v, bq0.v, acc_base, 0, 0, 0);

    auto gemm_tile = [&](int t0) {
        Frag a0, a1;
        a0.h[0] = *(const uint2*)&lds_kh[t0 + r][g * 8];
        a0.h[1] = *(const uint2*)&lds_kh[t0 + r][g * 8 + 4];
        a1.h[0] = *(const uint2*)&lds_kh[t0 + r][32 + g * 8];
        a1.h[1] = *(const uint2*)&lds_kh[t0 + r][32 + g * 8 + 4];
        f32x4 acc = __builtin_amdgcn_mfma_f32_16x16x32_bf16(a0.v, bf0.v, acc_base, 0, 0, 0);
        acc = __builtin_amdgcn_mfma_f32_16x16x32_bf16(a1.v, bf1.v, acc, 0, 0, 0);
        if (r < 8) {                 // D: col(j)=lane&15, row(t)=g*4+reg
            const int rr = t0 + (g << 2);
            lds_s[rr + 0][r] = acc[0];
            lds_s[rr + 1][r] = acc[1];
            lds_s[rr + 2][r] = acc[2];
            lds_s[rr + 3][r] = acc[3];
        }
    };
    auto stage4 = [&](const float4* Lv, int base) {
#pragma unroll
        for (int j = 0; j < 4; ++j) {
            int idx = base + (j << 8) + tid;
            float4 v = Lv[j];
            uint2 wp; wp.x = cvt_pk_bf16(v.x, v.y); wp.y = cvt_pk_bf16(v.z, v.w);
            *(uint2*)&lds_kh[idx >> 4][(idx & 15) << 2] = wp;
        }
    };

    // R0: tiles 0-3 (rows 0-63) || stage c1 (rows 64-127)
    gemm_tile(wave << 4);
    stage4(L1, 1024);
    BARRIER();
    // R1: tiles 4-7 || stage c2 (rows 128-191)
    gemm_tile((4 + wave) << 4);
    stage4(L2, 2048);
    BARRIER();
    // R2: tiles 8-11 || stage c3 (rows 192-199)
    gemm_tile((8 + wave) << 4);
    if (tid < 128) {
        int idx = 3072 + tid;
        float4 v = L3;
        uint2 wp; wp.x = cvt_pk_bf16(v.x, v.y); wp.y = cvt_pk_bf16(v.z, v.w);
        *(uint2*)&lds_kh[idx >> 4][(idx & 15) << 2] = wp;
    }
    BARRIER();
    // R3: clamped last tile (t0=184; rows 184-191 dup-computed, identical)
    if (wave == 0) gemm_tile(TT - 16);
    BARRIER();   // S complete

    // ---- MLP tail + fused esum: 200 threads, 1 row; weights via SCALAR loads ----
    float epart = 0.0f;
    if (tid < TT) {
        float4 s0 = *(const float4*)&lds_s[tid][0];
        float4 s1 = *(const float4*)&lds_s[tid][4];
        float h1[8];
        h1[0] = sigmoid_fast(s0.x + b1[0]);
        h1[1] = sigmoid_fast(s0.y + b1[1]);
        h1[2] = sigmoid_fast(s0.z + b1[2]);
        h1[3] = sigmoid_fast(s0.w + b1[3]);
        h1[4] = sigmoid_fast(s1.x + b1[4]);
        h1[5] = sigmoid_fast(s1.y + b1[5]);
        h1[6] = sigmoid_fast(s1.z + b1[6]);
        h1[7] = sigmoid_fast(s1.w + b1[7]);
        float sc = b3[0];
#pragma unroll
        for (int c = 0; c < 4; ++c) {
            float h = b2[c];
#pragma unroll
            for (int j = 0; j < 8; ++j)
                h = fmaf(h1[j], W2[j * 4 + c], h);   // uniform addr -> s_load
            sc = fmaf(sigmoid_fast(h), W3[c], sc);
        }
        float e = msk ? __expf(sc) : 0.0f;   // no-max softmax: |score| bounded
        lds_e[tid] = e;
        epart = e;
    }
#pragma unroll
    for (int off = 32; off; off >>= 1) epart += __shfl_xor(epart, off, 64);
    if (lane == 0) red[wave] = epart;
    BARRIER();   // B3: e + red ready; lds_s dead -> part alias live

    // ---- PV: wave w, half h -> t in [50w+25h, +25); e via readlane (VALU pipe) ----
    {
        const int half = lane >> 5;
        const int dp = lane & 31;
        const int d0 = dp << 1;
        const int tb = 50 * wave + 25 * half;
        // preload e for both halves (lanes 0..24 of each word used)
        float evA = lds_e[50 * wave + dp];        // h0 range
        float evB = lds_e[50 * wave + 25 + dp];   // h1 range (padded array: safe over-read)
        float acc0 = 0.0f, acc1 = 0.0f;
#pragma unroll
        for (int i = 0; i < 25; ++i) {
            u32 kw = *(const u32*)&lds_kh[tb + i][d0];   // all 32 banks, 2-way: free
            float eA = readlane_f(evA, i);
            float eB = readlane_f(evB, i);
            float e = half ? eB : eA;
            acc0 = fmaf(e, bflo(kw), acc0);
            acc1 = fmaf(e, bfhi(kw), acc1);
        }
        acc0 += __shfl_xor(acc0, 32, 64);   // combine the two halves (same dp)
        acc1 += __shfl_xor(acc1, 32, 64);
        if (half == 0) {
            float2 wpack; wpack.x = acc0; wpack.y = acc1;
            *(float2*)&part[wave * DD + d0] = wpack;
        }
    }
    BARRIER();   // B4: partials ready

    // ---- epilogue (wave 0): combine + store ----
    if (wave == 0) {
        float tot = red[0] + red[1] + red[2] + red[3];
        float rr = part[lane] + part[DD + lane] + part[2 * DD + lane] + part[3 * DD + lane];
        out[(size_t)b * DD + lane] = rr / tot;
    }
}

extern "C" void kernel_launch(void* const* d_in, const int* in_sizes, int n_in,
                              void* d_out, int out_size, void* d_ws, size_t ws_size,
                              hipStream_t stream) {
    const float* queries = (const float*)d_in[0];
    const float* keys    = (const float*)d_in[1];
    const int*   masks   = (const int*)d_in[2];
    const float* W1      = (const float*)d_in[3];
    const float* b1      = (const float*)d_in[4];
    const float* W2      = (const float*)d_in[5];
    const float* b2      = (const float*)d_in[6];
    const float* W3      = (const float*)d_in[7];
    const float* b3      = (const float*)d_in[8];
    float* out = (float*)d_out;

    const int B = in_sizes[0] / DD;  // 4096
    attn_pool_kernel<<<B, BLOCK, 0, stream>>>(queries, keys, masks, W1, b1, W2, b2, W3, b3, out);
}

// Round 14
// 38.450 us; speedup vs baseline: 1.0450x; 1.0406x over previous
//
#include <hip/hip_runtime.h>

#define TT 200
#define DD 64
#define BLOCK 256
#define KSH 68      // bf16 halfs per kh row: word-stride 34 = 2 mod 32 -> 2-way-free frag reads
#define CWS 132     // bf16 halfs per cwt row: word-stride 66 = 2 mod 32 -> 2-way-free

typedef unsigned short u16;
typedef unsigned int u32;
typedef __attribute__((ext_vector_type(8))) u16 ushort8;
typedef __attribute__((ext_vector_type(8))) short short8v;  // MFMA bf16x8 frag
typedef __attribute__((ext_vector_type(4))) float f32x4;    // MFMA acc

union Frag { uint2 h[2]; short8v v; };

__device__ __forceinline__ float bflo(u32 w) {
    union { u32 u; float f; } v; v.u = w << 16; return v.f;
}
__device__ __forceinline__ float bfhi(u32 w) {
    union { u32 u; float f; } v; v.u = w & 0xFFFF0000u; return v.f;
}
__device__ __forceinline__ float bf2f(u16 h) {
    union { u32 u; float f; } v; v.u = ((u32)h) << 16; return v.f;
}
__device__ __forceinline__ u16 f2bf(float f) {
    union { float f; u32 u; } v; v.f = f;
    return (u16)((v.u + 0x7FFFu + ((v.u >> 16) & 1u)) >> 16);
}
__device__ __forceinline__ u32 cvt_pk_bf16(float lo, float hi) {
    u32 r;
    asm("v_cvt_pk_bf16_f32 %0, %1, %2" : "=v"(r) : "v"(lo), "v"(hi));
    return r;
}
__device__ __forceinline__ float sigmoid_fast(float x) {
    return __builtin_amdgcn_rcpf(1.0f + __expf(-x));
}

// LDS-only barrier: drain LDS ops, sync, fence scheduler. NO vmcnt drain:
// in-flight chunk loads cross it (R8/R9/R11-validated).
#define BARRIER() do {                                              \
    asm volatile("s_waitcnt lgkmcnt(0)" ::: "memory");              \
    __builtin_amdgcn_sched_barrier(0);                              \
    __builtin_amdgcn_s_barrier();                                   \
    __builtin_amdgcn_sched_barrier(0);                              \
} while (0)

__global__ __launch_bounds__(BLOCK, 5) void attn_pool_kernel(
    const float* __restrict__ queries, const float* __restrict__ keys,
    const int* __restrict__ masks, const float* __restrict__ W1,
    const float* __restrict__ b1, const float* __restrict__ W2,
    const float* __restrict__ b2, const float* __restrict__ W3,
    const float* __restrict__ b3, float* __restrict__ out)
{
    __shared__ __align__(16) u16 lds_kh[TT][KSH];    // 27,200 B
    __shared__ __align__(16) u16 lds_cwt[8][CWS];    // 2,112 B  (B-frag reads use r&7; cols 64..127 = AC)
    __shared__ __align__(16) u16 lds_q16[DD];        // 128 B
    __shared__ __align__(16) u16 lds_s[TT][8];       // 3,200 B  scores bf16
    // total 32,640 B -> 5 blocks/CU.  e[200]+red[4] alias cwt (dead after frag loads);
    // part[4][64] aliases lds_s (dead after tail).
    float* lds_e = (float*)&lds_cwt[0][0];           // 800 B
    float* red   = lds_e + TT;                       // 16 B (816 <= 2,112)
    float* part  = (float*)&lds_s[0][0];             // 1,024 B <= 3,200

    const int b = blockIdx.x;
    const int tid = threadIdx.x;
    const int wave = tid >> 6;
    const int lane = tid & 63;

    // ======== P: issue K chunks 0,1 FIRST (oldest in vmcnt FIFO) ========
    const float4* kp = (const float4*)(keys + (size_t)b * TT * DD);
    float4 L0[4], L1[4], L2[4], L3;
#pragma unroll
    for (int j = 0; j < 4; ++j) L0[j] = kp[(j << 8) + tid];          // rows 0..63
#pragma unroll
    for (int j = 0; j < 4; ++j) L1[j] = kp[1024 + (j << 8) + tid];   // rows 64..127
    __builtin_amdgcn_sched_barrier(0);

    // ---- batch-scalar loads (younger than L0/L1) ----
    int m0 = 0, m1 = 0;
    if (tid < 100) {
        m0 = masks[(size_t)b * TT + tid];
        m1 = masks[(size_t)b * TT + tid + 100];
    }
    const int d_f = tid & 63;
    const int jr = tid >> 6;
    const float w1c0 = W1[(128 + d_f) * 8 + jr];
    const float wbc0 = W1[(64 + d_f) * 8 + jr] - w1c0;
    const float wd0  = W1[(192 + d_f) * 8 + jr];
    const float wac0 = W1[d_f * 8 + jr] + w1c0;
    const float w1c1 = W1[(128 + d_f) * 8 + jr + 4];
    const float wbc1 = W1[(64 + d_f) * 8 + jr + 4] - w1c1;
    const float wd1  = W1[(192 + d_f) * 8 + jr + 4];
    const float wac1 = W1[d_f * 8 + jr + 4] + w1c1;
    const float qd   = queries[(size_t)b * DD + d_f];
    __builtin_amdgcn_sched_barrier(0);

    // ---- stage c0 (waits L0 only; younger loads stay in flight) ----
#pragma unroll
    for (int j = 0; j < 4; ++j) {
        int idx = (j << 8) + tid;
        float4 v = L0[j];
        uint2 wp; wp.x = cvt_pk_bf16(v.x, v.y); wp.y = cvt_pk_bf16(v.z, v.w);
        *(uint2*)&lds_kh[idx >> 4][(idx & 15) << 2] = wp;
    }
    // ---- issue chunks 2,3 ----
#pragma unroll
    for (int j = 0; j < 4; ++j) L2[j] = kp[2048 + (j << 8) + tid];   // rows 128..191
    L3 = kp[3072 + (tid & 127)];                                     // rows 192..199 (dup for tid>=128)
    __builtin_amdgcn_sched_barrier(0);

    // ---- folds into cwt rows 0..7 (wait W1/q; L2/L3 younger -> in flight) ----
    // rows jr and jr+4 at col d_f: CW (q-dep) in cols 0..63, AC in cols 64..127
    lds_cwt[jr][64 + d_f]     = f2bf(wac0);
    lds_cwt[jr + 4][64 + d_f] = f2bf(wac1);
    lds_cwt[jr][d_f]          = f2bf(fmaf(qd, wd0, wbc0));
    lds_cwt[jr + 4][d_f]      = f2bf(fmaf(qd, wd1, wbc1));
    if (tid < DD) lds_q16[tid] = f2bf(qd);
    BARRIER();   // B1: c0 rows + cwt + q16 ready

    // ======== pipelined GEMM: compute chunk k || stage chunk k+1 ========
    const int r = lane & 15, g = lane >> 4;
    const int r7 = r & 7;      // cwt rows 8..15 fold onto 0..7 (S cols 8..15 discarded)
    Frag bf0, bf1, bq0, bq1, aq0, aq1;
    bf0.h[0] = *(const uint2*)&lds_cwt[r7][g * 8];
    bf0.h[1] = *(const uint2*)&lds_cwt[r7][g * 8 + 4];
    bf1.h[0] = *(const uint2*)&lds_cwt[r7][32 + g * 8];
    bf1.h[1] = *(const uint2*)&lds_cwt[r7][32 + g * 8 + 4];
    bq0.h[0] = *(const uint2*)&lds_cwt[r7][64 + g * 8];
    bq0.h[1] = *(const uint2*)&lds_cwt[r7][64 + g * 8 + 4];
    bq1.h[0] = *(const uint2*)&lds_cwt[r7][96 + g * 8];
    bq1.h[1] = *(const uint2*)&lds_cwt[r7][96 + g * 8 + 4];
    aq0.h[0] = *(const uint2*)&lds_q16[g * 8];
    aq0.h[1] = *(const uint2*)&lds_q16[g * 8 + 4];
    aq1.h[0] = *(const uint2*)&lds_q16[32 + g * 8];
    aq1.h[1] = *(const uint2*)&lds_q16[32 + g * 8 + 4];
    f32x4 zero = {0.0f, 0.0f, 0.0f, 0.0f};
    f32x4 acc_base = __builtin_amdgcn_mfma_f32_16x16x32_bf16(aq1.v, bq1.v, zero, 0, 0, 0);
    acc_base = __builtin_amdgcn_mfma_f32_16x16x32_bf16(aq0.v, bq0.v, acc_base, 0, 0, 0);

    auto gemm_tile = [&](int t0) {
        Frag a0, a1;
        a0.h[0] = *(const uint2*)&lds_kh[t0 + r][g * 8];
        a0.h[1] = *(const uint2*)&lds_kh[t0 + r][g * 8 + 4];
        a1.h[0] = *(const uint2*)&lds_kh[t0 + r][32 + g * 8];
        a1.h[1] = *(const uint2*)&lds_kh[t0 + r][32 + g * 8 + 4];
        f32x4 acc = __builtin_amdgcn_mfma_f32_16x16x32_bf16(a0.v, bf0.v, acc_base, 0, 0, 0);
        acc = __builtin_amdgcn_mfma_f32_16x16x32_bf16(a1.v, bf1.v, acc, 0, 0, 0);
        if (r < 8) {                 // D: col(j)=lane&15, row(t)=g*4+reg
            const int rr = t0 + (g << 2);
            lds_s[rr + 0][r] = f2bf(acc[0]);
            lds_s[rr + 1][r] = f2bf(acc[1]);
            lds_s[rr + 2][r] = f2bf(acc[2]);
            lds_s[rr + 3][r] = f2bf(acc[3]);
        }
    };
    auto stage4 = [&](const float4* Lv, int base) {
#pragma unroll
        for (int j = 0; j < 4; ++j) {
            int idx = base + (j << 8) + tid;
            float4 v = Lv[j];
            uint2 wp; wp.x = cvt_pk_bf16(v.x, v.y); wp.y = cvt_pk_bf16(v.z, v.w);
            *(uint2*)&lds_kh[idx >> 4][(idx & 15) << 2] = wp;
        }
    };

    // R0: tiles 0-3 (rows 0-63) || stage c1 (rows 64-127)
    gemm_tile(wave << 4);
    stage4(L1, 1024);
    BARRIER();
    // R1: tiles 4-7 || stage c2 (rows 128-191)
    gemm_tile((4 + wave) << 4);
    stage4(L2, 2048);
    BARRIER();
    // R2: tiles 8-11 || stage c3 (rows 192-199)
    gemm_tile((8 + wave) << 4);
    if (tid < 128) {
        int idx = 3072 + tid;
        float4 v = L3;
        uint2 wp; wp.x = cvt_pk_bf16(v.x, v.y); wp.y = cvt_pk_bf16(v.z, v.w);
        *(uint2*)&lds_kh[idx >> 4][(idx & 15) << 2] = wp;
    }
    BARRIER();
    // R3: clamped last tile (t0=184; rows 184-191 dup-computed, identical)
    if (wave == 0) gemm_tile(TT - 16);
    BARRIER();   // S complete; cwt dead -> e/red alias live

    // ---- MLP tail + fused esum: threads 0..99, rows (t, t+100); scalar weights ----
    float epart = 0.0f;
    if (tid < 100) {
        const int t0 = tid, t1 = tid + 100;
        ushort8 sa8 = *(const ushort8*)&lds_s[t0][0];
        ushort8 sb8 = *(const ushort8*)&lds_s[t1][0];
        float h1a[8], h1b[8];
#pragma unroll
        for (int j = 0; j < 8; ++j) {
            float bj = b1[j];                        // uniform -> s_load
            h1a[j] = sigmoid_fast(bf2f(sa8[j]) + bj);
            h1b[j] = sigmoid_fast(bf2f(sb8[j]) + bj);
        }
        float sa = b3[0], sb = b3[0];
#pragma unroll
        for (int c = 0; c < 4; ++c) {
            float ha = b2[c], hb = ha;
#pragma unroll
            for (int j = 0; j < 8; ++j) {
                float w2 = W2[j * 4 + c];            // uniform -> s_load
                ha = fmaf(h1a[j], w2, ha);
                hb = fmaf(h1b[j], w2, hb);
            }
            float w3 = W3[c];
            sa = fmaf(sigmoid_fast(ha), w3, sa);
            sb = fmaf(sigmoid_fast(hb), w3, sb);
        }
        float ea = m0 ? __expf(sa) : 0.0f;   // no-max softmax: |score| bounded
        float eb = m1 ? __expf(sb) : 0.0f;
        lds_e[t0] = ea;
        lds_e[t1] = eb;
        epart = ea + eb;
    }
#pragma unroll
    for (int off = 32; off; off >>= 1) epart += __shfl_xor(epart, off, 64);
    if (lane == 0) red[wave] = epart;
    BARRIER();   // B3: e + red ready; lds_s dead -> part alias live

    // ---- PV from bf16 kh (2-way-free): lane = (half, d-pair) ----
    {
        const int half = lane >> 5;
        const int dp = lane & 31;
        const int d0 = dp << 1;
        const int tbase = (wave << 1) + half;   // 0..7
        float acc0 = 0.0f, acc1 = 0.0f;
#pragma unroll
        for (int i = 0; i < 25; ++i) {
            const int t = tbase + (i << 3);
            u32 kw = *(const u32*)&lds_kh[t][d0];
            float e = lds_e[t];
            acc0 = fmaf(e, bflo(kw), acc0);
            acc1 = fmaf(e, bfhi(kw), acc1);
        }
        acc0 += __shfl_xor(acc0, 32, 64);
        acc1 += __shfl_xor(acc1, 32, 64);
        if (half == 0) {
            float2 wpack; wpack.x = acc0; wpack.y = acc1;
            *(float2*)&part[wave * DD + d0] = wpack;
        }
    }
    BARRIER();   // B4: partials ready

    // ---- epilogue (wave 0): combine + store ----
    if (wave == 0) {
        float tot = red[0] + red[1] + red[2] + red[3];
        float rr = part[lane] + part[DD + lane] + part[2 * DD + lane] + part[3 * DD + lane];
        out[(size_t)b * DD + lane] = rr / tot;
    }
}

extern "C" void kernel_launch(void* const* d_in, const int* in_sizes, int n_in,
                              void* d_out, int out_size, void* d_ws, size_t ws_size,
                              hipStream_t stream) {
    const float* queries = (const float*)d_in[0];
    const float* keys    = (const float*)d_in[1];
    const int*   masks   = (const int*)d_in[2];
    const float* W1      = (const float*)d_in[3];
    const float* b1      = (const float*)d_in[4];
    const float* W2      = (const float*)d_in[5];
    const float* b2      = (const float*)d_in[6];
    const float* W3      = (const float*)d_in[7];
    const float* b3      = (const float*)d_in[8];
    float* out = (float*)d_out;

    const int B = in_sizes[0] / DD;  // 4096
    attn_pool_kernel<<<B, BLOCK, 0, stream>>>(queries, keys, masks, W1, b1, W2, b2, W3, b3, out);
}